// Round 5
// baseline (118.676 us; speedup 1.0000x reference)
//
#include <hip/hip_runtime.h>
#include <math.h>

#define BATCH 8192
#define DIM   2048

// One wave per batch row. y is binary, so each coalesced int4 load (one
// 4-step granule) is packed to a 4-bit code and staged as ONE BYTE in LDS
// (ystage = 512 B/row vs 8 KB raw -> LDS 15 KB/block, 4 blocks/CU, and the
// main-loop y read is a single ds_read_b64 per lane). 8 timesteps fold into
// one 3x3 matmul against a 256-entry LDS table of 8-step products (12-float
// stride -> 3x ds_read_b128, conflict-light). t=0 is handled algebraically:
// log_prob = log(v^T P 1) with T^T v = pi, P = Prod_t M_{y_t} (uniform
// product over the full row, start state folded into v). Per-block partial
// means go through one atomicAdd each into d_out (zeroed by memsetAsync).
__global__ __launch_bounds__(256, 4)
void hmm_fwd(const int* __restrict__ y,
             const float* __restrict__ tp,
             const float* __restrict__ ep,
             const float* __restrict__ sp,
             float* __restrict__ out)
{
    __shared__ __align__(16) float t4[16 * 12];
    __shared__ __align__(16) float t8[256 * 12];
    __shared__ __align__(16) unsigned char ystage[4][512];
    __shared__ float blk[4];

    const int tid  = threadIdx.x;
    const int lane = tid & 63;
    const int wid  = tid >> 6;
    const int b    = blockIdx.x * 4 + wid;

    // ---- issue all coalesced loads first; params below hide the latency --
    const int* __restrict__ yb = y + (size_t)b * DIM;
    int4 v0l, v1l, v2l, v3l, v4l, v5l, v6l, v7l;
    {
        const int* p = yb + lane * 4;
        v0l = *reinterpret_cast<const int4*>(p + 0*256);
        v1l = *reinterpret_cast<const int4*>(p + 1*256);
        v2l = *reinterpret_cast<const int4*>(p + 2*256);
        v3l = *reinterpret_cast<const int4*>(p + 3*256);
        v4l = *reinterpret_cast<const int4*>(p + 4*256);
        v5l = *reinterpret_cast<const int4*>(p + 5*256);
        v6l = *reinterpret_cast<const int4*>(p + 6*256);
        v7l = *reinterpret_cast<const int4*>(p + 7*256);
    }

    // ---- normalized parameters (uniform per thread) ----
    float T[3][3], E[3][2], pi[3];
    #pragma unroll
    for (int i = 0; i < 3; ++i) {
        float a0 = tp[i*3+0], a1 = tp[i*3+1], a2 = tp[i*3+2];
        float mx = fmaxf(a0, fmaxf(a1, a2));
        float e0 = __expf(a0-mx), e1 = __expf(a1-mx), e2 = __expf(a2-mx);
        float inv = 1.0f / (e0+e1+e2);
        T[i][0] = e0*inv; T[i][1] = e1*inv; T[i][2] = e2*inv;
    }
    #pragma unroll
    for (int s = 0; s < 3; ++s) {
        float a0 = ep[s*2+0], a1 = ep[s*2+1];
        float mx = fmaxf(a0, a1);
        float e0 = __expf(a0-mx), e1 = __expf(a1-mx);
        float inv = 1.0f / (e0+e1);
        E[s][0] = e0*inv; E[s][1] = e1*inv;
    }
    {
        float a0 = sp[0], a1 = sp[1], a2 = sp[2];
        float mx = fmaxf(a0, fmaxf(a1, a2));
        float e0 = __expf(a0-mx), e1 = __expf(a1-mx), e2 = __expf(a2-mx);
        float inv = 1.0f / (e0+e1+e2);
        pi[0] = e0*inv; pi[1] = e1*inv; pi[2] = e2*inv;
    }

    // v solves T^T v = pi (adjugate solve); folds start vector + t=0 step
    float vx, vy, vz;
    {
        float c00 =  (T[1][1]*T[2][2] - T[1][2]*T[2][1]);
        float c01 = -(T[1][0]*T[2][2] - T[1][2]*T[2][0]);
        float c02 =  (T[1][0]*T[2][1] - T[1][1]*T[2][0]);
        float c10 = -(T[0][1]*T[2][2] - T[0][2]*T[2][1]);
        float c11 =  (T[0][0]*T[2][2] - T[0][2]*T[2][0]);
        float c12 = -(T[0][0]*T[2][1] - T[0][1]*T[2][0]);
        float c20 =  (T[0][1]*T[1][2] - T[0][2]*T[1][1]);
        float c21 = -(T[0][0]*T[1][2] - T[0][2]*T[1][0]);
        float c22 =  (T[0][0]*T[1][1] - T[0][1]*T[1][0]);
        float det = T[0][0]*c00 + T[0][1]*c01 + T[0][2]*c02;
        float invd = 1.0f / det;
        vx = (pi[0]*c00 + pi[1]*c01 + pi[2]*c02) * invd;
        vy = (pi[0]*c10 + pi[1]*c11 + pi[2]*c12) * invd;
        vz = (pi[0]*c20 + pi[1]*c21 + pi[2]*c22) * invd;
    }

    // per-step matrices M_y[k*3+j] = T[k][j] * E[j][y]
    float M0[9], M1[9];
    #pragma unroll
    for (int k = 0; k < 3; ++k)
        #pragma unroll
        for (int j = 0; j < 3; ++j) {
            M0[k*3+j] = T[k][j] * E[j][0];
            M1[k*3+j] = T[k][j] * E[j][1];
        }

    // ---- pack granules to 4-bit codes, stage one byte each ----
    {
        unsigned char* row = ystage[wid];
        int4 g[8] = {v0l,v1l,v2l,v3l,v4l,v5l,v6l,v7l};
        #pragma unroll
        for (int k = 0; k < 8; ++k)
            row[64*k + lane] =
                (unsigned char)(g[k].x | (g[k].y<<1) | (g[k].z<<2) | (g[k].w<<3));
    }

    // ---- build 4-step table on threads 0..15 ----
    if (tid < 16) {
        int code = tid;
        float A[9];
        const float* F0 = (code & 1) ? M1 : M0;
        #pragma unroll
        for (int e = 0; e < 9; ++e) A[e] = F0[e];
        code >>= 1;
        #pragma unroll
        for (int s = 1; s < 4; ++s) {
            const float* F = (code & 1) ? M1 : M0;
            code >>= 1;
            float Z[9];
            #pragma unroll
            for (int i = 0; i < 3; ++i)
                #pragma unroll
                for (int j = 0; j < 3; ++j)
                    Z[i*3+j] = fmaf(A[i*3+0], F[0*3+j],
                               fmaf(A[i*3+1], F[1*3+j], A[i*3+2]*F[2*3+j]));
            #pragma unroll
            for (int e = 0; e < 9; ++e) A[e] = Z[e];
        }
        #pragma unroll
        for (int e = 0; e < 9; ++e) t4[tid*12 + e] = A[e];
    }
    __syncthreads();   // covers t4 AND ystage

    // ---- 8-step table: t8[c] = t4[c&15] . t4[c>>4] ----
    {
        const float4* A4 = reinterpret_cast<const float4*>(&t4[(tid & 15) * 12]);
        const float4* B4 = reinterpret_cast<const float4*>(&t4[(tid >> 4) * 12]);
        float4 a0 = A4[0], a1 = A4[1], a2 = A4[2];
        float4 b0 = B4[0], b1 = B4[1], b2 = B4[2];
        float A[9] = {a0.x,a0.y,a0.z, a0.w,a1.x,a1.y, a1.z,a1.w,a2.x};
        float B[9] = {b0.x,b0.y,b0.z, b0.w,b1.x,b1.y, b1.z,b1.w,b2.x};
        float Z[9];
        #pragma unroll
        for (int i = 0; i < 3; ++i)
            #pragma unroll
            for (int j = 0; j < 3; ++j)
                Z[i*3+j] = fmaf(A[i*3+0], B[0*3+j],
                           fmaf(A[i*3+1], B[1*3+j], A[i*3+2]*B[2*3+j]));
        #pragma unroll
        for (int e = 0; e < 9; ++e) t8[tid*12 + e] = Z[e];
    }
    __syncthreads();

    // ---- per-lane chunk: 4 groups of 8 steps, codes from one b64 read ----
    uint2 q = *reinterpret_cast<const uint2*>(&ystage[wid][8 * lane]);

    float R[9] = {1.f,0.f,0.f, 0.f,1.f,0.f, 0.f,0.f,1.f};
    float lsc = 0.0f;

    #pragma unroll
    for (int j = 0; j < 4; ++j) {
        unsigned w  = (j < 2) ? q.x : q.y;
        unsigned sh = (j & 1) * 16;
        int idx = (int)(((w >> sh) & 15u) | ((w >> (sh + 4)) & 0xF0u));
        const float4* G4 = reinterpret_cast<const float4*>(&t8[idx * 12]);
        float4 p0 = G4[0], p1 = G4[1], p2 = G4[2];
        float g0 = p0.x, g1 = p0.y, g2 = p0.z,
              g3 = p0.w, g4 = p1.x, g5 = p1.y,
              g6 = p1.z, g7 = p1.w, g8 = p2.x;
        float nR[9];
        #pragma unroll
        for (int i = 0; i < 3; ++i) {
            nR[i*3+0] = fmaf(R[i*3+0], g0, fmaf(R[i*3+1], g3, R[i*3+2]*g6));
            nR[i*3+1] = fmaf(R[i*3+0], g1, fmaf(R[i*3+1], g4, R[i*3+2]*g7));
            nR[i*3+2] = fmaf(R[i*3+0], g2, fmaf(R[i*3+1], g5, R[i*3+2]*g8));
        }
        #pragma unroll
        for (int e = 0; e < 9; ++e) R[e] = nR[e];

        if (j == 1 || j == 3) {
            float m = R[0];
            #pragma unroll
            for (int e = 1; e < 9; ++e) m = fmaxf(m, R[e]);
            lsc += __logf(m);
            float inv = 1.0f / m;
            #pragma unroll
            for (int e = 0; e < 9; ++e) R[e] *= inv;
        }
    }

    // ---- ordered wave reduction: R_lane = R_lane @ R_{lane+offset} ----
    #pragma unroll
    for (int o = 1; o < 64; o <<= 1) {
        float S[9];
        #pragma unroll
        for (int e = 0; e < 9; ++e) S[e] = __shfl_down(R[e], o, 64);
        float osc = __shfl_down(lsc, o, 64);
        float nR[9];
        #pragma unroll
        for (int i = 0; i < 3; ++i)
            #pragma unroll
            for (int j = 0; j < 3; ++j)
                nR[i*3+j] = fmaf(R[i*3+0], S[0*3+j],
                            fmaf(R[i*3+1], S[1*3+j], R[i*3+2]*S[2*3+j]));
        #pragma unroll
        for (int e = 0; e < 9; ++e) R[e] = nR[e];
        lsc += osc;
    }

    // ---- block-level mean contribution: one atomic per block ----
    if (lane == 0) {
        float r0 = R[0] + R[1] + R[2];
        float r1 = R[3] + R[4] + R[5];
        float r2 = R[6] + R[7] + R[8];
        float p  = fmaf(vx, r0, fmaf(vy, r1, vz * r2));
        blk[wid] = __logf(p) + lsc;
    }
    __syncthreads();
    if (tid == 0) {
        float s = (blk[0] + blk[1] + blk[2] + blk[3]) * (1.0f / BATCH);
        atomicAdd(out, s);
    }
}

extern "C" void kernel_launch(void* const* d_in, const int* in_sizes, int n_in,
                              void* d_out, int out_size, void* d_ws, size_t ws_size,
                              hipStream_t stream)
{
    const int*   y  = (const int*)d_in[0];
    const float* tp = (const float*)d_in[1];
    const float* ep = (const float*)d_in[2];
    const float* sp = (const float*)d_in[3];
    float* out = (float*)d_out;

    hipMemsetAsync(out, 0, sizeof(float), stream);
    hmm_fwd<<<BATCH/4, 256, 0, stream>>>(y, tp, ep, sp, out);
}

// Round 6
// 116.319 us; speedup vs baseline: 1.0203x; 1.0203x over previous
//
#include <hip/hip_runtime.h>
#include <math.h>

#define BATCH 8192
#define DIM   2048

// One wave per batch row. y is binary: each coalesced int4 load (a 4-step
// granule) is packed to a 4-bit code and stored as ONE BYTE into LDS
// IMMEDIATELY (short register liveness — rounds 3 & 5 showed that holding
// the 8 int4s across the ~120-inst parameter section spills 32 VGPRs to
// scratch = 128 MB of extra HBM traffic). ystage is 512 B/row -> 15 KB
// LDS/block -> 4 blocks/CU. 8 timesteps fold into one 3x3 matmul against a
// 256-entry LDS table of 8-step products (12-float stride, ds_read_b128).
// t=0 is handled algebraically: log_prob = log(v^T P 1) with T^T v = pi,
// P = Prod_t M_{y_t} uniform over the full row. Per-block partial means are
// one atomicAdd each into d_out (zeroed by memsetAsync).
__global__ __launch_bounds__(256, 4)
void hmm_fwd(const int* __restrict__ y,
             const float* __restrict__ tp,
             const float* __restrict__ ep,
             const float* __restrict__ sp,
             float* __restrict__ out)
{
    __shared__ __align__(16) float t4[16 * 12];
    __shared__ __align__(16) float t8[256 * 12];
    __shared__ __align__(16) unsigned char ystage[4][512];
    __shared__ float blk[4];

    const int tid  = threadIdx.x;
    const int lane = tid & 63;
    const int wid  = tid >> 6;
    const int b    = blockIdx.x * 4 + wid;

    // ---- coalesced load -> pack -> byte store, fused (short liveness) ----
    {
        const int* __restrict__ p = y + (size_t)b * DIM + lane * 4;
        unsigned char* __restrict__ row = ystage[wid];
        #pragma unroll
        for (int g = 0; g < 8; ++g) {
            int4 v = *reinterpret_cast<const int4*>(p + g * 256);
            row[64*g + lane] =
                (unsigned char)(v.x | (v.y<<1) | (v.z<<2) | (v.w<<3));
        }
    }

    // ---- normalized parameters (uniform per thread) ----
    float T[3][3], E[3][2], pi[3];
    #pragma unroll
    for (int i = 0; i < 3; ++i) {
        float a0 = tp[i*3+0], a1 = tp[i*3+1], a2 = tp[i*3+2];
        float mx = fmaxf(a0, fmaxf(a1, a2));
        float e0 = __expf(a0-mx), e1 = __expf(a1-mx), e2 = __expf(a2-mx);
        float inv = 1.0f / (e0+e1+e2);
        T[i][0] = e0*inv; T[i][1] = e1*inv; T[i][2] = e2*inv;
    }
    #pragma unroll
    for (int s = 0; s < 3; ++s) {
        float a0 = ep[s*2+0], a1 = ep[s*2+1];
        float mx = fmaxf(a0, a1);
        float e0 = __expf(a0-mx), e1 = __expf(a1-mx);
        float inv = 1.0f / (e0+e1);
        E[s][0] = e0*inv; E[s][1] = e1*inv;
    }
    {
        float a0 = sp[0], a1 = sp[1], a2 = sp[2];
        float mx = fmaxf(a0, fmaxf(a1, a2));
        float e0 = __expf(a0-mx), e1 = __expf(a1-mx), e2 = __expf(a2-mx);
        float inv = 1.0f / (e0+e1+e2);
        pi[0] = e0*inv; pi[1] = e1*inv; pi[2] = e2*inv;
    }

    // v solves T^T v = pi (adjugate solve); folds start vector + t=0 step
    float vx, vy, vz;
    {
        float c00 =  (T[1][1]*T[2][2] - T[1][2]*T[2][1]);
        float c01 = -(T[1][0]*T[2][2] - T[1][2]*T[2][0]);
        float c02 =  (T[1][0]*T[2][1] - T[1][1]*T[2][0]);
        float c10 = -(T[0][1]*T[2][2] - T[0][2]*T[2][1]);
        float c11 =  (T[0][0]*T[2][2] - T[0][2]*T[2][0]);
        float c12 = -(T[0][0]*T[2][1] - T[0][1]*T[2][0]);
        float c20 =  (T[0][1]*T[1][2] - T[0][2]*T[1][1]);
        float c21 = -(T[0][0]*T[1][2] - T[0][2]*T[1][0]);
        float c22 =  (T[0][0]*T[1][1] - T[0][1]*T[1][0]);
        float det = T[0][0]*c00 + T[0][1]*c01 + T[0][2]*c02;
        float invd = 1.0f / det;
        vx = (pi[0]*c00 + pi[1]*c01 + pi[2]*c02) * invd;
        vy = (pi[0]*c10 + pi[1]*c11 + pi[2]*c12) * invd;
        vz = (pi[0]*c20 + pi[1]*c21 + pi[2]*c22) * invd;
    }

    // per-step matrices M_y[k*3+j] = T[k][j] * E[j][y]
    float M0[9], M1[9];
    #pragma unroll
    for (int k = 0; k < 3; ++k)
        #pragma unroll
        for (int j = 0; j < 3; ++j) {
            M0[k*3+j] = T[k][j] * E[j][0];
            M1[k*3+j] = T[k][j] * E[j][1];
        }

    // ---- build 4-step table on threads 0..15 ----
    if (tid < 16) {
        int code = tid;
        float A[9];
        const float* F0 = (code & 1) ? M1 : M0;
        #pragma unroll
        for (int e = 0; e < 9; ++e) A[e] = F0[e];
        code >>= 1;
        #pragma unroll
        for (int s = 1; s < 4; ++s) {
            const float* F = (code & 1) ? M1 : M0;
            code >>= 1;
            float Z[9];
            #pragma unroll
            for (int i = 0; i < 3; ++i)
                #pragma unroll
                for (int j = 0; j < 3; ++j)
                    Z[i*3+j] = fmaf(A[i*3+0], F[0*3+j],
                               fmaf(A[i*3+1], F[1*3+j], A[i*3+2]*F[2*3+j]));
            #pragma unroll
            for (int e = 0; e < 9; ++e) A[e] = Z[e];
        }
        #pragma unroll
        for (int e = 0; e < 9; ++e) t4[tid*12 + e] = A[e];
    }
    __syncthreads();   // covers t4 AND ystage

    // ---- 8-step table: t8[c] = t4[c&15] . t4[c>>4] ----
    {
        const float4* A4 = reinterpret_cast<const float4*>(&t4[(tid & 15) * 12]);
        const float4* B4 = reinterpret_cast<const float4*>(&t4[(tid >> 4) * 12]);
        float4 a0 = A4[0], a1 = A4[1], a2 = A4[2];
        float4 b0 = B4[0], b1 = B4[1], b2 = B4[2];
        float A[9] = {a0.x,a0.y,a0.z, a0.w,a1.x,a1.y, a1.z,a1.w,a2.x};
        float B[9] = {b0.x,b0.y,b0.z, b0.w,b1.x,b1.y, b1.z,b1.w,b2.x};
        float Z[9];
        #pragma unroll
        for (int i = 0; i < 3; ++i)
            #pragma unroll
            for (int j = 0; j < 3; ++j)
                Z[i*3+j] = fmaf(A[i*3+0], B[0*3+j],
                           fmaf(A[i*3+1], B[1*3+j], A[i*3+2]*B[2*3+j]));
        #pragma unroll
        for (int e = 0; e < 9; ++e) t8[tid*12 + e] = Z[e];
    }
    __syncthreads();

    // ---- per-lane chunk: 4 groups of 8 steps, codes from one b64 read ----
    uint2 q = *reinterpret_cast<const uint2*>(&ystage[wid][8 * lane]);

    float R[9] = {1.f,0.f,0.f, 0.f,1.f,0.f, 0.f,0.f,1.f};
    float lsc = 0.0f;

    #pragma unroll
    for (int j = 0; j < 4; ++j) {
        unsigned w  = (j < 2) ? q.x : q.y;
        unsigned sh = (j & 1) * 16;
        int idx = (int)(((w >> sh) & 15u) | ((w >> (sh + 4)) & 0xF0u));
        const float4* G4 = reinterpret_cast<const float4*>(&t8[idx * 12]);
        float4 p0 = G4[0], p1 = G4[1], p2 = G4[2];
        float g0 = p0.x, g1 = p0.y, g2 = p0.z,
              g3 = p0.w, g4 = p1.x, g5 = p1.y,
              g6 = p1.z, g7 = p1.w, g8 = p2.x;
        float nR[9];
        #pragma unroll
        for (int i = 0; i < 3; ++i) {
            nR[i*3+0] = fmaf(R[i*3+0], g0, fmaf(R[i*3+1], g3, R[i*3+2]*g6));
            nR[i*3+1] = fmaf(R[i*3+0], g1, fmaf(R[i*3+1], g4, R[i*3+2]*g7));
            nR[i*3+2] = fmaf(R[i*3+0], g2, fmaf(R[i*3+1], g5, R[i*3+2]*g8));
        }
        #pragma unroll
        for (int e = 0; e < 9; ++e) R[e] = nR[e];

        if (j == 1 || j == 3) {
            float m = R[0];
            #pragma unroll
            for (int e = 1; e < 9; ++e) m = fmaxf(m, R[e]);
            lsc += __logf(m);
            float inv = 1.0f / m;
            #pragma unroll
            for (int e = 0; e < 9; ++e) R[e] *= inv;
        }
    }

    // ---- ordered wave reduction: R_lane = R_lane @ R_{lane+offset} ----
    #pragma unroll
    for (int o = 1; o < 64; o <<= 1) {
        float S[9];
        #pragma unroll
        for (int e = 0; e < 9; ++e) S[e] = __shfl_down(R[e], o, 64);
        float osc = __shfl_down(lsc, o, 64);
        float nR[9];
        #pragma unroll
        for (int i = 0; i < 3; ++i)
            #pragma unroll
            for (int j = 0; j < 3; ++j)
                nR[i*3+j] = fmaf(R[i*3+0], S[0*3+j],
                            fmaf(R[i*3+1], S[1*3+j], R[i*3+2]*S[2*3+j]));
        #pragma unroll
        for (int e = 0; e < 9; ++e) R[e] = nR[e];
        lsc += osc;
    }

    // ---- block-level mean contribution: one atomic per block ----
    if (lane == 0) {
        float r0 = R[0] + R[1] + R[2];
        float r1 = R[3] + R[4] + R[5];
        float r2 = R[6] + R[7] + R[8];
        float p  = fmaf(vx, r0, fmaf(vy, r1, vz * r2));
        blk[wid] = __logf(p) + lsc;
    }
    __syncthreads();
    if (tid == 0) {
        float s = (blk[0] + blk[1] + blk[2] + blk[3]) * (1.0f / BATCH);
        atomicAdd(out, s);
    }
}

extern "C" void kernel_launch(void* const* d_in, const int* in_sizes, int n_in,
                              void* d_out, int out_size, void* d_ws, size_t ws_size,
                              hipStream_t stream)
{
    const int*   y  = (const int*)d_in[0];
    const float* tp = (const float*)d_in[1];
    const float* ep = (const float*)d_in[2];
    const float* sp = (const float*)d_in[3];
    float* out = (float*)d_out;

    hipMemsetAsync(out, 0, sizeof(float), stream);
    hmm_fwd<<<BATCH/4, 256, 0, stream>>>(y, tp, ep, sp, out);
}

// Round 7
// 101.806 us; speedup vs baseline: 1.1657x; 1.1426x over previous
//
#include <hip/hip_runtime.h>
#include <math.h>

#define BATCH 8192
#define DIM   2048

// One wave per batch row. y is binary: each coalesced int4 load (a 4-step
// granule) is packed to a 4-bit code and staged as ONE BYTE in LDS
// (ystage 512 B/row -> 15 KB LDS/block -> 4 blocks/CU; main-loop y read is
// a single ds_read_b64 per lane). 8 timesteps fold into one 3x3 matmul
// against a 256-entry LDS table of 8-step products (12-float stride ->
// ds_read_b128). t=0 handled algebraically: log_prob = log(v^T P 1) with
// T^T v = pi, P = Prod_t M_{y_t} uniform over the row.
// Output path: lane 0 writes the row log-prob to d_ws[b]; a tiny second
// kernel reduces 8192 -> mean. (Rounds 5/6 used one atomicAdd per block to
// a single address: 2048 serialized device-scope atomics cost ~12 us vs
// this scheme — measured regression 104.3 -> 116.3/118.7.)
__global__ __launch_bounds__(256, 4)
void hmm_fwd(const int* __restrict__ y,
             const float* __restrict__ tp,
             const float* __restrict__ ep,
             const float* __restrict__ sp,
             float* __restrict__ row_lp)
{
    __shared__ __align__(16) float t4[16 * 12];
    __shared__ __align__(16) float t8[256 * 12];
    __shared__ __align__(16) unsigned char ystage[4][512];

    const int tid  = threadIdx.x;
    const int lane = tid & 63;
    const int wid  = tid >> 6;
    const int b    = blockIdx.x * 4 + wid;

    // ---- coalesced load -> pack -> byte store ----
    {
        const int* __restrict__ p = y + (size_t)b * DIM + lane * 4;
        unsigned char* __restrict__ row = ystage[wid];
        #pragma unroll
        for (int g = 0; g < 8; ++g) {
            int4 v = *reinterpret_cast<const int4*>(p + g * 256);
            row[64*g + lane] =
                (unsigned char)(v.x | (v.y<<1) | (v.z<<2) | (v.w<<3));
        }
    }

    // ---- normalized parameters (uniform per thread) ----
    float T[3][3], E[3][2], pi[3];
    #pragma unroll
    for (int i = 0; i < 3; ++i) {
        float a0 = tp[i*3+0], a1 = tp[i*3+1], a2 = tp[i*3+2];
        float mx = fmaxf(a0, fmaxf(a1, a2));
        float e0 = __expf(a0-mx), e1 = __expf(a1-mx), e2 = __expf(a2-mx);
        float inv = 1.0f / (e0+e1+e2);
        T[i][0] = e0*inv; T[i][1] = e1*inv; T[i][2] = e2*inv;
    }
    #pragma unroll
    for (int s = 0; s < 3; ++s) {
        float a0 = ep[s*2+0], a1 = ep[s*2+1];
        float mx = fmaxf(a0, a1);
        float e0 = __expf(a0-mx), e1 = __expf(a1-mx);
        float inv = 1.0f / (e0+e1);
        E[s][0] = e0*inv; E[s][1] = e1*inv;
    }
    {
        float a0 = sp[0], a1 = sp[1], a2 = sp[2];
        float mx = fmaxf(a0, fmaxf(a1, a2));
        float e0 = __expf(a0-mx), e1 = __expf(a1-mx), e2 = __expf(a2-mx);
        float inv = 1.0f / (e0+e1+e2);
        pi[0] = e0*inv; pi[1] = e1*inv; pi[2] = e2*inv;
    }

    // v solves T^T v = pi (adjugate solve); folds start vector + t=0 step
    float vx, vy, vz;
    {
        float c00 =  (T[1][1]*T[2][2] - T[1][2]*T[2][1]);
        float c01 = -(T[1][0]*T[2][2] - T[1][2]*T[2][0]);
        float c02 =  (T[1][0]*T[2][1] - T[1][1]*T[2][0]);
        float c10 = -(T[0][1]*T[2][2] - T[0][2]*T[2][1]);
        float c11 =  (T[0][0]*T[2][2] - T[0][2]*T[2][0]);
        float c12 = -(T[0][0]*T[2][1] - T[0][1]*T[2][0]);
        float c20 =  (T[0][1]*T[1][2] - T[0][2]*T[1][1]);
        float c21 = -(T[0][0]*T[1][2] - T[0][2]*T[1][0]);
        float c22 =  (T[0][0]*T[1][1] - T[0][1]*T[1][0]);
        float det = T[0][0]*c00 + T[0][1]*c01 + T[0][2]*c02;
        float invd = 1.0f / det;
        vx = (pi[0]*c00 + pi[1]*c01 + pi[2]*c02) * invd;
        vy = (pi[0]*c10 + pi[1]*c11 + pi[2]*c12) * invd;
        vz = (pi[0]*c20 + pi[1]*c21 + pi[2]*c22) * invd;
    }

    // per-step matrices M_y[k*3+j] = T[k][j] * E[j][y]
    float M0[9], M1[9];
    #pragma unroll
    for (int k = 0; k < 3; ++k)
        #pragma unroll
        for (int j = 0; j < 3; ++j) {
            M0[k*3+j] = T[k][j] * E[j][0];
            M1[k*3+j] = T[k][j] * E[j][1];
        }

    // ---- build 4-step table on threads 0..15 ----
    if (tid < 16) {
        int code = tid;
        float A[9];
        const float* F0 = (code & 1) ? M1 : M0;
        #pragma unroll
        for (int e = 0; e < 9; ++e) A[e] = F0[e];
        code >>= 1;
        #pragma unroll
        for (int s = 1; s < 4; ++s) {
            const float* F = (code & 1) ? M1 : M0;
            code >>= 1;
            float Z[9];
            #pragma unroll
            for (int i = 0; i < 3; ++i)
                #pragma unroll
                for (int j = 0; j < 3; ++j)
                    Z[i*3+j] = fmaf(A[i*3+0], F[0*3+j],
                               fmaf(A[i*3+1], F[1*3+j], A[i*3+2]*F[2*3+j]));
            #pragma unroll
            for (int e = 0; e < 9; ++e) A[e] = Z[e];
        }
        #pragma unroll
        for (int e = 0; e < 9; ++e) t4[tid*12 + e] = A[e];
    }
    __syncthreads();   // covers t4 AND ystage

    // ---- 8-step table: t8[c] = t4[c&15] . t4[c>>4] ----
    {
        const float4* A4 = reinterpret_cast<const float4*>(&t4[(tid & 15) * 12]);
        const float4* B4 = reinterpret_cast<const float4*>(&t4[(tid >> 4) * 12]);
        float4 a0 = A4[0], a1 = A4[1], a2 = A4[2];
        float4 b0 = B4[0], b1 = B4[1], b2 = B4[2];
        float A[9] = {a0.x,a0.y,a0.z, a0.w,a1.x,a1.y, a1.z,a1.w,a2.x};
        float B[9] = {b0.x,b0.y,b0.z, b0.w,b1.x,b1.y, b1.z,b1.w,b2.x};
        float Z[9];
        #pragma unroll
        for (int i = 0; i < 3; ++i)
            #pragma unroll
            for (int j = 0; j < 3; ++j)
                Z[i*3+j] = fmaf(A[i*3+0], B[0*3+j],
                           fmaf(A[i*3+1], B[1*3+j], A[i*3+2]*B[2*3+j]));
        #pragma unroll
        for (int e = 0; e < 9; ++e) t8[tid*12 + e] = Z[e];
    }
    __syncthreads();

    // ---- per-lane chunk: 4 groups of 8 steps, codes from one b64 read ----
    uint2 q = *reinterpret_cast<const uint2*>(&ystage[wid][8 * lane]);

    float R[9] = {1.f,0.f,0.f, 0.f,1.f,0.f, 0.f,0.f,1.f};
    float lsc = 0.0f;

    #pragma unroll
    for (int j = 0; j < 4; ++j) {
        unsigned w  = (j < 2) ? q.x : q.y;
        unsigned sh = (j & 1) * 16;
        int idx = (int)(((w >> sh) & 15u) | ((w >> (sh + 4)) & 0xF0u));
        const float4* G4 = reinterpret_cast<const float4*>(&t8[idx * 12]);
        float4 p0 = G4[0], p1 = G4[1], p2 = G4[2];
        float g0 = p0.x, g1 = p0.y, g2 = p0.z,
              g3 = p0.w, g4 = p1.x, g5 = p1.y,
              g6 = p1.z, g7 = p1.w, g8 = p2.x;
        float nR[9];
        #pragma unroll
        for (int i = 0; i < 3; ++i) {
            nR[i*3+0] = fmaf(R[i*3+0], g0, fmaf(R[i*3+1], g3, R[i*3+2]*g6));
            nR[i*3+1] = fmaf(R[i*3+0], g1, fmaf(R[i*3+1], g4, R[i*3+2]*g7));
            nR[i*3+2] = fmaf(R[i*3+0], g2, fmaf(R[i*3+1], g5, R[i*3+2]*g8));
        }
        #pragma unroll
        for (int e = 0; e < 9; ++e) R[e] = nR[e];

        if (j == 1 || j == 3) {
            float m = R[0];
            #pragma unroll
            for (int e = 1; e < 9; ++e) m = fmaxf(m, R[e]);
            lsc += __logf(m);
            float inv = 1.0f / m;
            #pragma unroll
            for (int e = 0; e < 9; ++e) R[e] *= inv;
        }
    }

    // ---- ordered wave reduction: R_lane = R_lane @ R_{lane+offset} ----
    #pragma unroll
    for (int o = 1; o < 64; o <<= 1) {
        float S[9];
        #pragma unroll
        for (int e = 0; e < 9; ++e) S[e] = __shfl_down(R[e], o, 64);
        float osc = __shfl_down(lsc, o, 64);
        float nR[9];
        #pragma unroll
        for (int i = 0; i < 3; ++i)
            #pragma unroll
            for (int j = 0; j < 3; ++j)
                nR[i*3+j] = fmaf(R[i*3+0], S[0*3+j],
                            fmaf(R[i*3+1], S[1*3+j], R[i*3+2]*S[2*3+j]));
        #pragma unroll
        for (int e = 0; e < 9; ++e) R[e] = nR[e];
        lsc += osc;
    }

    // ---- lane 0: row log-prob to workspace (no atomics, no extra sync) ----
    if (lane == 0) {
        float r0 = R[0] + R[1] + R[2];
        float r1 = R[3] + R[4] + R[5];
        float r2 = R[6] + R[7] + R[8];
        float p  = fmaf(vx, r0, fmaf(vy, r1, vz * r2));
        row_lp[b] = __logf(p) + lsc;
    }
}

__global__ void reduce_mean(const float* __restrict__ row, float* __restrict__ out)
{
    float s = 0.0f;
    for (int i = threadIdx.x; i < BATCH; i += 1024) s += row[i];
    #pragma unroll
    for (int o = 32; o > 0; o >>= 1) s += __shfl_down(s, o, 64);
    __shared__ float sm[16];
    int w = threadIdx.x >> 6;
    if ((threadIdx.x & 63) == 0) sm[w] = s;
    __syncthreads();
    if (threadIdx.x == 0) {
        float t = 0.0f;
        #pragma unroll
        for (int i = 0; i < 16; ++i) t += sm[i];
        out[0] = t * (1.0f / BATCH);
    }
}

extern "C" void kernel_launch(void* const* d_in, const int* in_sizes, int n_in,
                              void* d_out, int out_size, void* d_ws, size_t ws_size,
                              hipStream_t stream)
{
    const int*   y  = (const int*)d_in[0];
    const float* tp = (const float*)d_in[1];
    const float* ep = (const float*)d_in[2];
    const float* sp = (const float*)d_in[3];
    float* out = (float*)d_out;
    float* row = (float*)d_ws;   // 32 KB of the workspace

    hmm_fwd<<<BATCH/4, 256, 0, stream>>>(y, tp, ep, sp, row);
    reduce_mean<<<1, 1024, 0, stream>>>(row, out);
}

// Round 8
// 101.305 us; speedup vs baseline: 1.1715x; 1.0049x over previous
//
#include <hip/hip_runtime.h>
#include <math.h>

#define BATCH 8192
#define DIM   2048

// One wave per batch row. y is binary: each coalesced int4 load (a 4-step
// granule) packs to a 4-bit code staged as ONE BYTE in LDS (512 B/row ->
// 15 KB LDS/block; main-loop y read is one ds_read_b64/lane). 8 timesteps
// fold into one 3x3 matmul against a 256-entry LDS table of 8-step products
// (12-float stride -> ds_read_b128). t=0 handled algebraically:
// log_prob = log(v^T P 1), T^T v = pi, P = Prod_t M_{y_t}.
// R8: parameter normalization (11 expf + solves, ~200 insts) runs ONLY on
// wave 0 — threads 0..15 build t4, thread 0 writes the row-independent v to
// LDS; waves 1..3 skip params entirely (saves ~37% of grid-wide issue).
// launch_bounds(256,6) -> 6 blocks/CU (was 4). Output: row log-probs to
// d_ws, tiny reduce kernel (atomics to one address cost +12us, r5/r6).
__global__ __launch_bounds__(256, 6)
void hmm_fwd(const int* __restrict__ y,
             const float* __restrict__ tp,
             const float* __restrict__ ep,
             const float* __restrict__ sp,
             float* __restrict__ row_lp)
{
    __shared__ __align__(16) float t4[16 * 12];
    __shared__ __align__(16) float t8[256 * 12];
    __shared__ __align__(16) unsigned char ystage[4][512];
    __shared__ float vlds[3];

    const int tid  = threadIdx.x;
    const int lane = tid & 63;
    const int wid  = tid >> 6;
    const int b    = blockIdx.x * 4 + wid;

    // ---- coalesced load -> pack -> byte store (all threads) ----
    {
        const int* __restrict__ p = y + (size_t)b * DIM + lane * 4;
        unsigned char* __restrict__ row = ystage[wid];
        #pragma unroll
        for (int g = 0; g < 8; ++g) {
            int4 v = *reinterpret_cast<const int4*>(p + g * 256);
            row[64*g + lane] =
                (unsigned char)(v.x | (v.y<<1) | (v.z<<2) | (v.w<<3));
        }
    }

    // ---- wave 0 only: params, v-solve, 4-step table ----
    if (wid == 0) {
        float T[3][3], E[3][2], pi[3];
        #pragma unroll
        for (int i = 0; i < 3; ++i) {
            float a0 = tp[i*3+0], a1 = tp[i*3+1], a2 = tp[i*3+2];
            float mx = fmaxf(a0, fmaxf(a1, a2));
            float e0 = __expf(a0-mx), e1 = __expf(a1-mx), e2 = __expf(a2-mx);
            float inv = 1.0f / (e0+e1+e2);
            T[i][0] = e0*inv; T[i][1] = e1*inv; T[i][2] = e2*inv;
        }
        #pragma unroll
        for (int s = 0; s < 3; ++s) {
            float a0 = ep[s*2+0], a1 = ep[s*2+1];
            float mx = fmaxf(a0, a1);
            float e0 = __expf(a0-mx), e1 = __expf(a1-mx);
            float inv = 1.0f / (e0+e1);
            E[s][0] = e0*inv; E[s][1] = e1*inv;
        }
        {
            float a0 = sp[0], a1 = sp[1], a2 = sp[2];
            float mx = fmaxf(a0, fmaxf(a1, a2));
            float e0 = __expf(a0-mx), e1 = __expf(a1-mx), e2 = __expf(a2-mx);
            float inv = 1.0f / (e0+e1+e2);
            pi[0] = e0*inv; pi[1] = e1*inv; pi[2] = e2*inv;
        }

        if (lane == 0) {   // v solves T^T v = pi; row-independent
            float c00 =  (T[1][1]*T[2][2] - T[1][2]*T[2][1]);
            float c01 = -(T[1][0]*T[2][2] - T[1][2]*T[2][0]);
            float c02 =  (T[1][0]*T[2][1] - T[1][1]*T[2][0]);
            float c10 = -(T[0][1]*T[2][2] - T[0][2]*T[2][1]);
            float c11 =  (T[0][0]*T[2][2] - T[0][2]*T[2][0]);
            float c12 = -(T[0][0]*T[2][1] - T[0][1]*T[2][0]);
            float c20 =  (T[0][1]*T[1][2] - T[0][2]*T[1][1]);
            float c21 = -(T[0][0]*T[1][2] - T[0][2]*T[1][0]);
            float c22 =  (T[0][0]*T[1][1] - T[0][1]*T[1][0]);
            float det = T[0][0]*c00 + T[0][1]*c01 + T[0][2]*c02;
            float invd = 1.0f / det;
            vlds[0] = (pi[0]*c00 + pi[1]*c01 + pi[2]*c02) * invd;
            vlds[1] = (pi[0]*c10 + pi[1]*c11 + pi[2]*c12) * invd;
            vlds[2] = (pi[0]*c20 + pi[1]*c21 + pi[2]*c22) * invd;
        }

        // per-step matrices M_y[k*3+j] = T[k][j] * E[j][y]
        float M0[9], M1[9];
        #pragma unroll
        for (int k = 0; k < 3; ++k)
            #pragma unroll
            for (int j = 0; j < 3; ++j) {
                M0[k*3+j] = T[k][j] * E[j][0];
                M1[k*3+j] = T[k][j] * E[j][1];
            }

        if (lane < 16) {   // 4-step table
            int code = lane;
            float A[9];
            const float* F0 = (code & 1) ? M1 : M0;
            #pragma unroll
            for (int e = 0; e < 9; ++e) A[e] = F0[e];
            code >>= 1;
            #pragma unroll
            for (int s = 1; s < 4; ++s) {
                const float* F = (code & 1) ? M1 : M0;
                code >>= 1;
                float Z[9];
                #pragma unroll
                for (int i = 0; i < 3; ++i)
                    #pragma unroll
                    for (int j = 0; j < 3; ++j)
                        Z[i*3+j] = fmaf(A[i*3+0], F[0*3+j],
                                   fmaf(A[i*3+1], F[1*3+j], A[i*3+2]*F[2*3+j]));
                #pragma unroll
                for (int e = 0; e < 9; ++e) A[e] = Z[e];
            }
            #pragma unroll
            for (int e = 0; e < 9; ++e) t4[lane*12 + e] = A[e];
        }
    }
    __syncthreads();   // covers t4, vlds AND ystage

    // ---- 8-step table: t8[c] = t4[c&15] . t4[c>>4] (all 256 threads) ----
    {
        const float4* A4 = reinterpret_cast<const float4*>(&t4[(tid & 15) * 12]);
        const float4* B4 = reinterpret_cast<const float4*>(&t4[(tid >> 4) * 12]);
        float4 a0 = A4[0], a1 = A4[1], a2 = A4[2];
        float4 b0 = B4[0], b1 = B4[1], b2 = B4[2];
        float A[9] = {a0.x,a0.y,a0.z, a0.w,a1.x,a1.y, a1.z,a1.w,a2.x};
        float B[9] = {b0.x,b0.y,b0.z, b0.w,b1.x,b1.y, b1.z,b1.w,b2.x};
        float Z[9];
        #pragma unroll
        for (int i = 0; i < 3; ++i)
            #pragma unroll
            for (int j = 0; j < 3; ++j)
                Z[i*3+j] = fmaf(A[i*3+0], B[0*3+j],
                           fmaf(A[i*3+1], B[1*3+j], A[i*3+2]*B[2*3+j]));
        #pragma unroll
        for (int e = 0; e < 9; ++e) t8[tid*12 + e] = Z[e];
    }
    __syncthreads();

    // ---- per-lane chunk: 4 groups of 8 steps, codes from one b64 read ----
    uint2 q = *reinterpret_cast<const uint2*>(&ystage[wid][8 * lane]);

    float R[9] = {1.f,0.f,0.f, 0.f,1.f,0.f, 0.f,0.f,1.f};
    float lsc = 0.0f;

    #pragma unroll
    for (int j = 0; j < 4; ++j) {
        unsigned w  = (j < 2) ? q.x : q.y;
        unsigned sh = (j & 1) * 16;
        int idx = (int)(((w >> sh) & 15u) | ((w >> (sh + 4)) & 0xF0u));
        const float4* G4 = reinterpret_cast<const float4*>(&t8[idx * 12]);
        float4 p0 = G4[0], p1 = G4[1], p2 = G4[2];
        float g0 = p0.x, g1 = p0.y, g2 = p0.z,
              g3 = p0.w, g4 = p1.x, g5 = p1.y,
              g6 = p1.z, g7 = p1.w, g8 = p2.x;
        float nR[9];
        #pragma unroll
        for (int i = 0; i < 3; ++i) {
            nR[i*3+0] = fmaf(R[i*3+0], g0, fmaf(R[i*3+1], g3, R[i*3+2]*g6));
            nR[i*3+1] = fmaf(R[i*3+0], g1, fmaf(R[i*3+1], g4, R[i*3+2]*g7));
            nR[i*3+2] = fmaf(R[i*3+0], g2, fmaf(R[i*3+1], g5, R[i*3+2]*g8));
        }
        #pragma unroll
        for (int e = 0; e < 9; ++e) R[e] = nR[e];

        if (j == 1 || j == 3) {
            float m = R[0];
            #pragma unroll
            for (int e = 1; e < 9; ++e) m = fmaxf(m, R[e]);
            lsc += __logf(m);
            float inv = 1.0f / m;
            #pragma unroll
            for (int e = 0; e < 9; ++e) R[e] *= inv;
        }
    }

    // ---- ordered wave reduction: R_lane = R_lane @ R_{lane+offset} ----
    #pragma unroll
    for (int o = 1; o < 64; o <<= 1) {
        float S[9];
        #pragma unroll
        for (int e = 0; e < 9; ++e) S[e] = __shfl_down(R[e], o, 64);
        float osc = __shfl_down(lsc, o, 64);
        float nR[9];
        #pragma unroll
        for (int i = 0; i < 3; ++i)
            #pragma unroll
            for (int j = 0; j < 3; ++j)
                nR[i*3+j] = fmaf(R[i*3+0], S[0*3+j],
                            fmaf(R[i*3+1], S[1*3+j], R[i*3+2]*S[2*3+j]));
        #pragma unroll
        for (int e = 0; e < 9; ++e) R[e] = nR[e];
        lsc += osc;
    }

    // ---- lane 0: row log-prob to workspace ----
    if (lane == 0) {
        float r0 = R[0] + R[1] + R[2];
        float r1 = R[3] + R[4] + R[5];
        float r2 = R[6] + R[7] + R[8];
        float p  = fmaf(vlds[0], r0, fmaf(vlds[1], r1, vlds[2] * r2));
        row_lp[b] = __logf(p) + lsc;
    }
}

__global__ void reduce_mean(const float* __restrict__ row, float* __restrict__ out)
{
    float s = 0.0f;
    for (int i = threadIdx.x; i < BATCH; i += 1024) s += row[i];
    #pragma unroll
    for (int o = 32; o > 0; o >>= 1) s += __shfl_down(s, o, 64);
    __shared__ float sm[16];
    int w = threadIdx.x >> 6;
    if ((threadIdx.x & 63) == 0) sm[w] = s;
    __syncthreads();
    if (threadIdx.x == 0) {
        float t = 0.0f;
        #pragma unroll
        for (int i = 0; i < 16; ++i) t += sm[i];
        out[0] = t * (1.0f / BATCH);
    }
}

extern "C" void kernel_launch(void* const* d_in, const int* in_sizes, int n_in,
                              void* d_out, int out_size, void* d_ws, size_t ws_size,
                              hipStream_t stream)
{
    const int*   y  = (const int*)d_in[0];
    const float* tp = (const float*)d_in[1];
    const float* ep = (const float*)d_in[2];
    const float* sp = (const float*)d_in[3];
    float* out = (float*)d_out;
    float* row = (float*)d_ws;   // 32 KB of the workspace

    hmm_fwd<<<BATCH/4, 256, 0, stream>>>(y, tp, ep, sp, row);
    reduce_mean<<<1, 1024, 0, stream>>>(row, out);
}